// Round 1
// baseline (25684.387 us; speedup 1.0000x reference)
//
#include <hip/hip_runtime.h>
#include <hip/hip_bf16.h>
#include <math.h>

// GPT-2 forward, fp32 baseline. B=2,T=1024,C=768,H=12,D=64,L=12,VP=50304.
#define BB 2
#define TT 1024
#define CC 768
#define NH 12
#define HD 64
#define NL 12
#define VP 50304
#define MM (BB * TT)   // 2048 rows

__device__ __forceinline__ float gelu_tanh(float x) {
    const float k = 0.7978845608028654f;  // sqrt(2/pi)
    float x3 = x * x * x;
    return 0.5f * x * (1.0f + tanhf(k * (x + 0.044715f * x3)));
}

// ---------------- embedding: x[b,t,c] = wte[idx[b,t],c] + wpe[t,c] ----------
__global__ void embed_kernel(const int* __restrict__ idx,
                             const float* __restrict__ wte,
                             const float* __restrict__ wpe,
                             float* __restrict__ x, int n) {
    int i = blockIdx.x * blockDim.x + threadIdx.x;
    if (i >= n) return;
    int c = i % CC;
    int bt = i / CC;
    int t = bt % TT;
    x[i] = wte[(size_t)idx[bt] * CC + c] + wpe[(size_t)t * CC + c];
}

// ---------------- layernorm: one 256-thread block per row (C=768=3*256) ----
__launch_bounds__(256)
__global__ void ln_kernel(const float* __restrict__ x,
                          const float* __restrict__ w,
                          const float* __restrict__ b,
                          float* __restrict__ out) {
    int row = blockIdx.x;
    int tid = threadIdx.x;
    const float* xr = x + (size_t)row * CC;
    __shared__ float red[256];
    float v0 = xr[tid], v1 = xr[tid + 256], v2 = xr[tid + 512];
    red[tid] = v0 + v1 + v2;
    __syncthreads();
    for (int s = 128; s > 0; s >>= 1) {
        if (tid < s) red[tid] += red[tid + s];
        __syncthreads();
    }
    float mu = red[0] * (1.0f / CC);
    __syncthreads();
    float d0 = v0 - mu, d1 = v1 - mu, d2 = v2 - mu;
    red[tid] = d0 * d0 + d1 * d1 + d2 * d2;
    __syncthreads();
    for (int s = 128; s > 0; s >>= 1) {
        if (tid < s) red[tid] += red[tid + s];
        __syncthreads();
    }
    float rstd = rsqrtf(red[0] * (1.0f / CC) + 1e-5f);
    float* outr = out + (size_t)row * CC;
    outr[tid]       = d0 * rstd * w[tid]       + b[tid];
    outr[tid + 256] = d1 * rstd * w[tid + 256] + b[tid + 256];
    outr[tid + 512] = d2 * rstd * w[tid + 512] + b[tid + 512];
}

// ---------------- GEMM: out[m,n] = (res?) + bias[n] + sum_k A[m,k]*W[n,k] ---
// A: (M,K) row-major.  W: (N,K) row-major (i.e. computes A @ W^T).
// 64x64 block tile, 256 threads, 4x4 per thread, BK=16.
// M,N multiples of 64; K multiple of 16 (all shapes here satisfy this).
template <bool GELU, bool RES>
__launch_bounds__(256)
__global__ void gemm_kernel(const float* __restrict__ A,
                            const float* __restrict__ W,
                            const float* __restrict__ bias,
                            const float* __restrict__ res,
                            float* __restrict__ out,
                            int M, int N, int K) {
    __shared__ float As[16][65];
    __shared__ float Ws[16][65];
    const int tid = threadIdx.x;
    const int tx = tid & 15, ty = tid >> 4;
    const int bm = blockIdx.y * 64, bn = blockIdx.x * 64;
    const int lrow = tid >> 2;       // 0..63
    const int lk = (tid & 3) * 4;    // 0,4,8,12
    const float* Arow = A + (size_t)(bm + lrow) * K + lk;
    const float* Wrow = W + (size_t)(bn + lrow) * K + lk;
    float acc[4][4] = {};
    for (int k0 = 0; k0 < K; k0 += 16) {
        float4 av = *(const float4*)(Arow + k0);
        float4 wv = *(const float4*)(Wrow + k0);
        As[lk + 0][lrow] = av.x; As[lk + 1][lrow] = av.y;
        As[lk + 2][lrow] = av.z; As[lk + 3][lrow] = av.w;
        Ws[lk + 0][lrow] = wv.x; Ws[lk + 1][lrow] = wv.y;
        Ws[lk + 2][lrow] = wv.z; Ws[lk + 3][lrow] = wv.w;
        __syncthreads();
#pragma unroll
        for (int kk = 0; kk < 16; ++kk) {
            float a0 = As[kk][ty * 4 + 0], a1 = As[kk][ty * 4 + 1];
            float a2 = As[kk][ty * 4 + 2], a3 = As[kk][ty * 4 + 3];
            float b0 = Ws[kk][tx * 4 + 0], b1 = Ws[kk][tx * 4 + 1];
            float b2 = Ws[kk][tx * 4 + 2], b3 = Ws[kk][tx * 4 + 3];
            acc[0][0] += a0 * b0; acc[0][1] += a0 * b1; acc[0][2] += a0 * b2; acc[0][3] += a0 * b3;
            acc[1][0] += a1 * b0; acc[1][1] += a1 * b1; acc[1][2] += a1 * b2; acc[1][3] += a1 * b3;
            acc[2][0] += a2 * b0; acc[2][1] += a2 * b1; acc[2][2] += a2 * b2; acc[2][3] += a2 * b3;
            acc[3][0] += a3 * b0; acc[3][1] += a3 * b1; acc[3][2] += a3 * b2; acc[3][3] += a3 * b3;
        }
        __syncthreads();
    }
#pragma unroll
    for (int i = 0; i < 4; ++i) {
        int m = bm + ty * 4 + i;
#pragma unroll
        for (int j = 0; j < 4; ++j) {
            int n = bn + tx * 4 + j;
            float v = acc[i][j];
            if (bias) v += bias[n];
            if (GELU) v = gelu_tanh(v);
            if (RES) v += res[(size_t)m * N + n];
            out[(size_t)m * N + n] = v;
        }
    }
}

// ---------------- attention: one wave per (b,h,q); lane = head dim ---------
// qkv layout: (B,T,3C); q at [.., h*64+d], k at [.., C + h*64+d], v at [.., 2C+..]
__launch_bounds__(64)
__global__ void attn_kernel(const float* __restrict__ qkv,
                            float* __restrict__ y) {
    int lane = threadIdx.x;
    int q = blockIdx.x % TT;
    int bh = blockIdx.x / TT;
    int h = bh % NH;
    int b = bh / NH;
    const float scale = 0.125f;  // 1/sqrt(64)
    const size_t base = ((size_t)(b * TT) * 3 * CC);
    float qf = qkv[base + (size_t)q * 3 * CC + h * HD + lane];
    float m = -INFINITY, l = 0.0f, acc = 0.0f;
    for (int k = 0; k <= q; ++k) {
        size_t koff = base + (size_t)k * 3 * CC + h * HD + lane;
        float kf = qkv[koff + CC];
        float s = qf * kf;
#pragma unroll
        for (int off = 32; off > 0; off >>= 1) s += __shfl_xor(s, off);
        s *= scale;
        float mn = fmaxf(m, s);
        float p = expf(s - mn);
        float corr = expf(m - mn);  // exp(-inf - mn) = 0 on first iter
        float vf = qkv[koff + 2 * CC];
        l = l * corr + p;
        acc = acc * corr + p * vf;
        m = mn;
    }
    y[((size_t)(b * TT + q)) * CC + h * HD + lane] = acc / l;
}

extern "C" void kernel_launch(void* const* d_in, const int* in_sizes, int n_in,
                              void* d_out, int out_size, void* d_ws, size_t ws_size,
                              hipStream_t stream) {
    const int*   idx     = (const int*)d_in[0];
    const float* wte     = (const float*)d_in[1];
    const float* wpe     = (const float*)d_in[2];
    const float* ln1w    = (const float*)d_in[3];
    const float* ln1b    = (const float*)d_in[4];
    const float* qkvw    = (const float*)d_in[5];
    const float* qkvb    = (const float*)d_in[6];
    const float* projw   = (const float*)d_in[7];
    const float* projb   = (const float*)d_in[8];
    const float* ln2w    = (const float*)d_in[9];
    const float* ln2b    = (const float*)d_in[10];
    const float* fcw     = (const float*)d_in[11];
    const float* fcb     = (const float*)d_in[12];
    const float* fcprojw = (const float*)d_in[13];
    const float* fcprojb = (const float*)d_in[14];
    const float* lnfw    = (const float*)d_in[15];
    const float* lnfb    = (const float*)d_in[16];
    float* logits = (float*)d_out;

    // workspace layout (floats)
    float* ws = (float*)d_ws;
    const size_t xn = (size_t)MM * CC;          // 1,572,864
    float* x   = ws;                            // residual stream
    float* h   = x + xn;                        // LN output
    float* y   = h + xn;                        // attention output
    float* big = y + xn;                        // qkv (2048x2304) / fc act (2048x3072)
    float* qkv = big;
    float* hfc = big;

    const int M = MM;
    dim3 tb(256);

    // embedding
    {
        int n = (int)xn;
        embed_kernel<<<(n + 255) / 256, tb, 0, stream>>>(idx, wte, wpe, x, n);
    }

    for (int l = 0; l < NL; ++l) {
        // LN1
        ln_kernel<<<M, tb, 0, stream>>>(x, ln1w + l * CC, ln1b + l * CC, h);
        // qkv = h @ qkvw^T + qkvb   (N = 2304)
        gemm_kernel<false, false><<<dim3(2304 / 64, M / 64), tb, 0, stream>>>(
            h, qkvw + (size_t)l * 3 * CC * CC, qkvb + (size_t)l * 3 * CC,
            nullptr, qkv, M, 3 * CC, CC);
        // attention
        attn_kernel<<<BB * NH * TT, dim3(64), 0, stream>>>(qkv, y);
        // x = x + y @ projw^T + projb  (N = 768)
        gemm_kernel<false, true><<<dim3(CC / 64, M / 64), tb, 0, stream>>>(
            y, projw + (size_t)l * CC * CC, projb + (size_t)l * CC,
            x, x, M, CC, CC);
        // LN2
        ln_kernel<<<M, tb, 0, stream>>>(x, ln2w + l * CC, ln2b + l * CC, h);
        // hfc = gelu(h @ fcw^T + fcb)  (N = 3072)
        gemm_kernel<true, false><<<dim3(4 * CC / 64, M / 64), tb, 0, stream>>>(
            h, fcw + (size_t)l * 4 * CC * CC, fcb + (size_t)l * 4 * CC,
            nullptr, hfc, M, 4 * CC, CC);
        // x = x + hfc @ fcprojw^T + fcprojb  (K = 3072)
        gemm_kernel<false, true><<<dim3(CC / 64, M / 64), tb, 0, stream>>>(
            hfc, fcprojw + (size_t)l * CC * 4 * CC, fcprojb + (size_t)l * CC,
            x, x, M, CC, 4 * CC);
    }

    // final LN
    ln_kernel<<<M, tb, 0, stream>>>(x, lnfw, lnfb, h);
    // logits = h @ wte^T  (N = 50304, no bias)
    gemm_kernel<false, false><<<dim3(VP / 64, M / 64), tb, 0, stream>>>(
        h, wte, nullptr, nullptr, logits, M, VP, CC);
}